// Round 16
// baseline (60.477 us; speedup 1.0000x reference)
//
#include <hip/hip_runtime.h>
#include <cmath>

#define NB 4
#define NS 1024
#define NH 16
#define ND 64
#define LOG2E 1.44269504f

typedef __attribute__((ext_vector_type(8))) short bf16x8;
typedef __attribute__((ext_vector_type(4))) short short4v;
typedef __attribute__((ext_vector_type(4))) float f32x4;

static __device__ __forceinline__ short f2bf(float x) {
  __bf16 h = (__bf16)x;
  return __builtin_bit_cast(short, h);
}

static __device__ __forceinline__ float fast_exp2(float x) {
#if __has_builtin(__builtin_amdgcn_exp2f)
  return __builtin_amdgcn_exp2f(x);
#else
  return exp2f(x);
#endif
}

__global__ __launch_bounds__(512, 2)
void fsa_fwd(const float* __restrict__ qkv,
             const float* __restrict__ bias,
             float* __restrict__ out)
{
  // XCD-chunked swizzle, batch-fastest logical order. grid=512, bijective. (R3/R10)
  const int hw = blockIdx.x;
  const int lg = ((hw & 7) << 6) | (hw >> 3);
  const int b  = lg & 3;
  const int qt = (lg >> 2) & 7;       // 8 q-tiles of 128 rows
  const int h  = lg >> 5;

  const int tid  = threadIdx.x;
  const int w    = tid >> 6;          // wave 0..7, owns q-rows q0+w*16..+15
  const int lane = tid & 63;
  const int lo   = lane & 15;
  const int hi   = lane >> 4;
  const int q0   = qt * 128;

  __shared__ __attribute__((aligned(16))) short Ksh[64 * 64];   // [t][d] XOR-swizzled rows (8 KB)
  __shared__ __attribute__((aligned(16))) short VTsh[64 * 64];  // [d][t] packed-pair XOR-swizzled (8 KB)
  __shared__ __attribute__((aligned(16))) short Psh[8][16 * 64];// per-wave P strip [q][t], XOR-swizzled (16 KB)

  // ---- Q fragments (B-operand of swapped QK^T; same element layout), pre-scaled ----
  bf16x8 qf[2];
  {
    const int qs = q0 + w * 16 + lo;
    const float* qp = qkv + ((size_t)(b * NS + qs) * 3) * (NH * ND) + h * ND + hi * 8;
    #pragma unroll
    for (int f = 0; f < 2; ++f) {
      float4 x0 = *(const float4*)(qp + f * 32);
      float4 x1 = *(const float4*)(qp + f * 32 + 4);
      float v[8] = {x0.x, x0.y, x0.z, x0.w, x1.x, x1.y, x1.z, x1.w};
      #pragma unroll
      for (int j = 0; j < 8; ++j) qf[f][j] = f2bf(v[j] * (0.125f * LOG2E));
    }
  }

  const size_t tstr = 3 * NH * ND;  // 3072 floats per s-step
  const float* kg = qkv + (size_t)b * NS * tstr + 1 * NH * ND + h * ND;
  const float* vg = qkv + (size_t)b * NS * tstr + 2 * NH * ND + h * ND;

  // staging split across 512 threads (R10 geometry, use-site loads)
  const int krow = tid >> 3;          // 0..63
  const int kd   = (tid & 7) * 8;     // 8 floats per thread
  const int vrow = (tid & 31) * 2;    // t pair
  const int vd   = (tid >> 5) * 4;    // 4 d's per thread

  // bias^T: lane owns q-row q0+w*16+lo; float4 over t = t0+tt*16+hi*4..+3 (R9 pattern)
  const float* bbT = bias + (size_t)h * NS * NS + (size_t)(q0 + w * 16 + lo) * NS + hi * 4;

  float psum = 0.f;
  f32x4 oacc[4];
  #pragma unroll
  for (int dt = 0; dt < 4; ++dt) { f32x4 z = {0.f, 0.f, 0.f, 0.f}; oacc[dt] = z; }

  #pragma unroll 1
  for (int it = 0; it < 16; ++it) {
    const int t0 = it * 64;

    // ---- load + convert K rows (8 f32 -> 1 b128 write) ----
    bf16x8 w0;
    {
      const float* src = kg + (size_t)(t0 + krow) * tstr + kd;
      float4 a = ((const float4*)src)[0];
      float4 c = ((const float4*)src)[1];
      float v[8] = {a.x,a.y,a.z,a.w, c.x,c.y,c.z,c.w};
      #pragma unroll
      for (int j = 0; j < 8; ++j) w0[j] = f2bf(v[j]);
    }
    // ---- load + convert V (2 t-rows x 4 d, packed pairs) ----
    unsigned vpk[4];
    {
      const float* s0 = vg + (size_t)(t0 + vrow) * tstr + vd;
      const float* s1 = s0 + tstr;
      float4 a0 = *(const float4*)s0;
      float4 b0 = *(const float4*)s1;
      float r0[4] = {a0.x,a0.y,a0.z,a0.w};
      float r1[4] = {b0.x,b0.y,b0.z,b0.w};
      #pragma unroll
      for (int j = 0; j < 4; ++j)
        vpk[j] = (unsigned)(unsigned short)f2bf(r0[j]) |
                 ((unsigned)(unsigned short)f2bf(r1[j]) << 16);
    }

    __syncthreads();  // prior iteration's K/VT LDS reads complete

    {
      const int base = krow * 64 + kd;
      const int sw = (krow & 7) << 3;
      *(bf16x8*)&Ksh[base ^ sw] = w0;
    }
    {
      unsigned* vt32 = (unsigned*)VTsh;
      #pragma unroll
      for (int j = 0; j < 4; ++j) {
        const int R = vd + j;
        vt32[R * 32 + ((vrow >> 1) ^ ((R & 7) << 2))] = vpk[j];
      }
    }

    // ---- bias^T for this tile: 4 float4 loads (use-site; TLP hides) ----
    float4 brT[4];
    #pragma unroll
    for (int tt = 0; tt < 4; ++tt)
      brT[tt] = *(const float4*)(bbT + t0 + tt * 16);

    __syncthreads();  // K/VT tile visible in LDS

    __builtin_amdgcn_s_setprio(1);
    // ---- swapped QK^T: S^T = K x Q, acc init = bias^T*log2e - 8*log2e ----
    f32x4 sacc[4];
    #pragma unroll
    for (int tt = 0; tt < 4; ++tt) {
      f32x4 sb;
      #pragma unroll
      for (int r = 0; r < 4; ++r) sb[r] = fmaf(brT[tt][r], LOG2E, -8.f * LOG2E);
      const int kr = tt * 16 + lo;
      const int ksw = (kr & 7) << 3;
      bf16x8 a0 = *(const bf16x8*)&Ksh[(kr * 64      + hi * 8) ^ ksw];
      bf16x8 a1 = *(const bf16x8*)&Ksh[(kr * 64 + 32 + hi * 8) ^ ksw];
      sb = __builtin_amdgcn_mfma_f32_16x16x32_bf16(a0, qf[0], sb, 0, 0, 0);
      sb = __builtin_amdgcn_mfma_f32_16x16x32_bf16(a1, qf[1], sb, 0, 0, 0);
      sacc[tt] = sb;
    }

    // ---- P^T = exp2(S^T); lane holds t = tt*16+hi*4+r contiguous -> b64 packed writes ----
    // P strip layout [q=lo][t], swizzle t ^= (lo&7)<<3 (bits 3-5; commutes with +r, +j)
    short* pw = Psh[w];
    {
      const int psw = (lo & 7) << 3;
      #pragma unroll
      for (int tt = 0; tt < 4; ++tt) {
        short4v pk;
        #pragma unroll
        for (int r = 0; r < 4; ++r) {
          float p = fast_exp2(sacc[tt][r]);
          psum += p;                 // lane's q=lo row, its own t-subset
          pk[r] = f2bf(p);
        }
        *(short4v*)&pw[lo * 64 + ((tt * 16 + hi * 4) ^ psw)] = pk;
      }
    }
    asm volatile("s_waitcnt lgkmcnt(0)" ::: "memory");

    // ---- PV (R10 wide form): A = P[q][t] (2 b128), B = VT rows ----
    bf16x8 pf0, pf1;
    {
      const int psw = (lo & 7) << 3;
      pf0 = *(const bf16x8*)&pw[lo * 64 + ((     hi * 8) ^ psw)];
      pf1 = *(const bf16x8*)&pw[lo * 64 + ((32 + hi * 8) ^ psw)];
    }
    #pragma unroll
    for (int dt = 0; dt < 4; ++dt) {
      const int vr = dt * 16 + lo;
      const int vsw = (vr & 7) << 3;
      bf16x8 v0 = *(const bf16x8*)&VTsh[vr * 64 + ((     hi * 8) ^ vsw)];
      bf16x8 v1 = *(const bf16x8*)&VTsh[vr * 64 + ((32 + hi * 8) ^ vsw)];
      oacc[dt] = __builtin_amdgcn_mfma_f32_16x16x32_bf16(pf0, v0, oacc[dt], 0, 0, 0);
      oacc[dt] = __builtin_amdgcn_mfma_f32_16x16x32_bf16(pf1, v1, oacc[dt], 0, 0, 0);
    }
    __builtin_amdgcn_s_setprio(0);
  }

  // ---- psum: reduce over hi groups (lane's q-row = lo) ----
  psum += __shfl_xor(psum, 16, 64);
  psum += __shfl_xor(psum, 32, 64);

  // ---- epilogue: lane writes rows hi*4+r, col lo; gather psum via shfl ----
  float* ob = out + ((size_t)(b * NS + q0 + w * 16 + hi * 4) * NH + h) * ND + lo;
  #pragma unroll
  for (int r = 0; r < 4; ++r) {
    const float inv = 1.f / __shfl(psum, hi * 4 + r, 64);
    #pragma unroll
    for (int dt = 0; dt < 4; ++dt)
      ob[(size_t)r * NH * ND + dt * 16] = oacc[dt][r] * inv;
  }
}

extern "C" void kernel_launch(void* const* d_in, const int* in_sizes, int n_in,
                              void* d_out, int out_size, void* d_ws, size_t ws_size,
                              hipStream_t stream) {
  const float* qkv  = (const float*)d_in[0];
  const float* bias = (const float*)d_in[1];
  float* out = (float*)d_out;
  dim3 grid(NB * NH * (NS / 128));
  fsa_fwd<<<grid, 512, 0, stream>>>(qkv, bias, out);
}

// Round 17
// 51.366 us; speedup vs baseline: 1.1774x; 1.1774x over previous
//
#include <hip/hip_runtime.h>

#define NB 4
#define NS 1024
#define NH 16
#define ND 64

typedef __attribute__((ext_vector_type(8))) short bf16x8;
typedef __attribute__((ext_vector_type(4))) float f32x4;

static __device__ __forceinline__ short f2bf(float x) {
  __bf16 h = (__bf16)x;
  return __builtin_bit_cast(short, h);
}
static __device__ __forceinline__ float bf2f(short s) {
  unsigned u = ((unsigned)(unsigned short)s) << 16;
  return __builtin_bit_cast(float, u);
}

__global__ __launch_bounds__(512, 2)
void fsa_fwd(const float* __restrict__ qkv,
             const float* __restrict__ bias,
             float* __restrict__ out)
{
  // XCD-chunked swizzle, batch-fastest logical order. grid=512, bijective. (R10)
  const int hw = blockIdx.x;
  const int lg = ((hw & 7) << 6) | (hw >> 3);
  const int b  = lg & 3;
  const int qt = (lg >> 2) & 7;       // 8 q-tiles of 128 rows
  const int h  = lg >> 5;

  const int tid  = threadIdx.x;
  const int w    = tid >> 6;          // wave 0..7
  const int lane = tid & 63;
  const int lo   = lane & 15;
  const int hi   = lane >> 4;
  const int q0   = qt * 128;

  __shared__ __attribute__((aligned(16))) short Ksh[2][64 * 64];   // double-buffered (16 KB)
  __shared__ __attribute__((aligned(16))) short VTsh[2][64 * 64];  // double-buffered (16 KB)
  __shared__ __attribute__((aligned(16))) short Psh[8][16 * 64];   // per-wave P strip (16 KB)

  // ---- Q fragments (A-operand), pre-scaled by 1/8 (R10) ----
  bf16x8 qf[2];
  {
    const int qs = q0 + w * 16 + lo;
    const float* qp = qkv + ((size_t)(b * NS + qs) * 3) * (NH * ND) + h * ND + hi * 8;
    #pragma unroll
    for (int f = 0; f < 2; ++f) {
      float4 x0 = *(const float4*)(qp + f * 32);
      float4 x1 = *(const float4*)(qp + f * 32 + 4);
      float v[8] = {x0.x, x0.y, x0.z, x0.w, x1.x, x1.y, x1.z, x1.w};
      #pragma unroll
      for (int j = 0; j < 8; ++j) qf[f][j] = f2bf(v[j] * 0.125f);
    }
  }

  const size_t tstr = 3 * NH * ND;  // 3072 floats per s-step
  const float* kg = qkv + (size_t)b * NS * tstr + 1 * NH * ND + h * ND;
  const float* vg = qkv + (size_t)b * NS * tstr + 2 * NH * ND + h * ND;

  // staging split across 512 threads (R10 geometry, use-site loads)
  const int krow = tid >> 3;          // 0..63
  const int kd   = (tid & 7) * 8;     // 8 floats per thread
  const int vrow = (tid & 31) * 2;    // t pair
  const int vd   = (tid >> 5) * 4;    // 4 d's per thread

  const float* bb = bias + (size_t)h * NS * NS + (size_t)(q0 + w * 16 + hi * 4) * NS + lo;

  float psum[4] = {0.f, 0.f, 0.f, 0.f};
  f32x4 oacc[4];
  #pragma unroll
  for (int dt = 0; dt < 4; ++dt) { f32x4 z = {0.f, 0.f, 0.f, 0.f}; oacc[dt] = z; }

  // stage tile T0 into buffer BUF: use-site loads, cvt, ds_write (R10 patterns)
#define STAGE(T0, BUF) do { \
    bf16x8 w0_; \
    { \
      const float* src_ = kg + (size_t)((T0) + krow) * tstr + kd; \
      float4 a_ = ((const float4*)src_)[0]; \
      float4 c_ = ((const float4*)src_)[1]; \
      float v_[8] = {a_.x,a_.y,a_.z,a_.w, c_.x,c_.y,c_.z,c_.w}; \
      _Pragma("unroll") \
      for (int j_ = 0; j_ < 8; ++j_) w0_[j_] = f2bf(v_[j_]); \
    } \
    unsigned vpk_[4]; \
    { \
      const float* s0_ = vg + (size_t)((T0) + vrow) * tstr + vd; \
      const float* s1_ = s0_ + tstr; \
      float4 a0_ = *(const float4*)s0_; \
      float4 b0_ = *(const float4*)s1_; \
      float r0_[4] = {a0_.x,a0_.y,a0_.z,a0_.w}; \
      float r1_[4] = {b0_.x,b0_.y,b0_.z,b0_.w}; \
      _Pragma("unroll") \
      for (int j_ = 0; j_ < 4; ++j_) \
        vpk_[j_] = (unsigned)(unsigned short)f2bf(r0_[j_]) | \
                   ((unsigned)(unsigned short)f2bf(r1_[j_]) << 16); \
    } \
    { \
      const int base_ = krow * 64 + kd; \
      const int sw_ = (krow & 7) << 3; \
      *(bf16x8*)&Ksh[BUF][base_ ^ sw_] = w0_; \
    } \
    { \
      unsigned* vt_ = (unsigned*)VTsh[BUF]; \
      _Pragma("unroll") \
      for (int j_ = 0; j_ < 4; ++j_) { \
        const int R_ = vd + j_; \
        vt_[R_ * 32 + ((vrow >> 1) ^ ((R_ & 7) << 2))] = vpk_[j_]; \
      } \
    } \
  } while (0)

  // ---- prologue: stage tile 0 into buf 0 ----
  STAGE(0, 0);
  __syncthreads();

  #pragma unroll 1
  for (int it = 0; it < 16; ++it) {
    const int cur = it & 1;
    const int t0 = it * 64;

    // stage tile it+1 into the other buffer — its ds_writes need not complete
    // until the end-of-iteration barrier, so they overlap this tile's compute.
    if (it < 15) STAGE(t0 + 64, cur ^ 1);

    // ---- bias for this tile (use-site; TLP hides it — R10) ----
    float br[4][4];
    #pragma unroll
    for (int r = 0; r < 4; ++r)
      #pragma unroll
      for (int tt = 0; tt < 4; ++tt)
        br[r][tt] = bb[(size_t)r * NS + t0 + tt * 16];

    __builtin_amdgcn_s_setprio(1);
    // ---- QK^T: acc init = bias - 8 (const-shift softmax) ----
    f32x4 sacc[4];
    #pragma unroll
    for (int tt = 0; tt < 4; ++tt) {
      f32x4 sb;
      #pragma unroll
      for (int r = 0; r < 4; ++r) sb[r] = br[r][tt] - 8.f;
      const int kr = tt * 16 + lo;
      const int ksw = (kr & 7) << 3;
      bf16x8 k0 = *(const bf16x8*)&Ksh[cur][(kr * 64      + hi * 8) ^ ksw];
      bf16x8 k1 = *(const bf16x8*)&Ksh[cur][(kr * 64 + 32 + hi * 8) ^ ksw];
      sb = __builtin_amdgcn_mfma_f32_16x16x32_bf16(qf[0], k0, sb, 0, 0, 0);
      sb = __builtin_amdgcn_mfma_f32_16x16x32_bf16(qf[1], k1, sb, 0, 0, 0);
      sacc[tt] = sb;
    }

    // ---- P = exp(s), per-lane psum, per-wave P strip (R10) ----
    short* pw = Psh[w];
    #pragma unroll
    for (int r = 0; r < 4; ++r) {
      const int row = hi * 4 + r;
      const int sw = (row & 7) << 3;
      #pragma unroll
      for (int tt = 0; tt < 4; ++tt) {
        float p = __expf(sacc[tt][r]);
        short pb = f2bf(p);
        psum[r] += bf2f(pb);
        pw[row * 64 + ((tt * 16 + lo) ^ sw)] = pb;
      }
    }
    asm volatile("s_waitcnt lgkmcnt(0)" ::: "memory");

    // ---- PV (R10) ----
    bf16x8 pf0, pf1;
    {
      const int psw = (lo & 7) << 3;
      pf0 = *(const bf16x8*)&pw[lo * 64 + ((     hi * 8) ^ psw)];
      pf1 = *(const bf16x8*)&pw[lo * 64 + ((32 + hi * 8) ^ psw)];
    }
    #pragma unroll
    for (int dt = 0; dt < 4; ++dt) {
      const int vr = dt * 16 + lo;
      const int vsw = (vr & 7) << 3;
      bf16x8 v0 = *(const bf16x8*)&VTsh[cur][vr * 64 + ((     hi * 8) ^ vsw)];
      bf16x8 v1 = *(const bf16x8*)&VTsh[cur][vr * 64 + ((32 + hi * 8) ^ vsw)];
      oacc[dt] = __builtin_amdgcn_mfma_f32_16x16x32_bf16(pf0, v0, oacc[dt], 0, 0, 0);
      oacc[dt] = __builtin_amdgcn_mfma_f32_16x16x32_bf16(pf1, v1, oacc[dt], 0, 0, 0);
    }
    __builtin_amdgcn_s_setprio(0);

    __syncthreads();   // single barrier: buf[cur^1] writes done, buf[cur] reads done
  }

#undef STAGE

  // ---- final row-sum reduction (once) ----
  #pragma unroll
  for (int r = 0; r < 4; ++r) {
    psum[r] += __shfl_xor(psum[r], 1, 64);
    psum[r] += __shfl_xor(psum[r], 2, 64);
    psum[r] += __shfl_xor(psum[r], 4, 64);
    psum[r] += __shfl_xor(psum[r], 8, 64);
  }

  // ---- epilogue: out[b][s][h][d] ----
  float* ob = out + ((size_t)(b * NS + q0 + w * 16 + hi * 4) * NH + h) * ND + lo;
  #pragma unroll
  for (int r = 0; r < 4; ++r) {
    float inv = 1.f / psum[r];
    #pragma unroll
    for (int dt = 0; dt < 4; ++dt)
      ob[(size_t)r * NH * ND + dt * 16] = oacc[dt][r] * inv;
  }
}

extern "C" void kernel_launch(void* const* d_in, const int* in_sizes, int n_in,
                              void* d_out, int out_size, void* d_ws, size_t ws_size,
                              hipStream_t stream) {
  const float* qkv  = (const float*)d_in[0];
  const float* bias = (const float*)d_in[1];
  float* out = (float*)d_out;
  dim3 grid(NB * NH * (NS / 128));
  fsa_fwd<<<grid, 512, 0, stream>>>(qkv, bias, out);
}